// Round 11
// baseline (3725.642 us; speedup 1.0000x reference)
//
#include <hip/hip_runtime.h>
#include <math.h>

// Problem constants
#define NB   16
#define CC   256
#define NPTS 16384       // 16*32*32
#define KK   8192
#define Z_OUT 4194304    // NPTS*CC
// d_out: [0,Z_OUT) z_q_out (BCHW), [Z_OUT,Z_OUT+NPTS) idx as float, [Z_OUT+NPTS] loss
// d_out scratch: zb16 = bf16[16384][256] at slot 0, ebf = bf16[8192][256] at slot
// 2,097,152 -- both dead once k_cand completes; k_final overwrites with z_q BCHW.

// ws layout (floats)
#define WS_ENORM 16448
#define WS_CCNT  24640                // int[16384] candidate counts
#define WS_CIDX  41024                // int[16384][64] candidate k lists
#define CAND_CAP 64
#define LCAP     32                   // per-third per-n LDS list capacity
#define MARGIN   4.0e-4f              // > 2*eps_bf16 + d-quantum + enorm spread

typedef short v8s __attribute__((ext_vector_type(8)));
typedef float v4f __attribute__((ext_vector_type(4)));

__device__ __forceinline__ void gl_lds16(const void* g, void* l) {
    __builtin_amdgcn_global_load_lds((const __attribute__((address_space(1))) void*)g,
                                     (__attribute__((address_space(3))) void*)l, 16, 0, 0);
}
__device__ __forceinline__ unsigned short f2bf(float f) {   // RNE, finite inputs
    unsigned int u = __float_as_uint(f);
    return (unsigned short)((u + 0x7FFFu + ((u >> 16) & 1u)) >> 16);
}
// monotone float<->uint encoding for atomicMax on floats of any sign
__device__ __forceinline__ unsigned fenc(float f) {
    unsigned u = __float_as_uint(f);
    return (u & 0x80000000u) ? ~u : (u | 0x80000000u);
}
__device__ __forceinline__ float fdec(unsigned m) {
    unsigned u = (m & 0x80000000u) ? (m & 0x7fffffffu) : ~m;
    return __uint_as_float(u);
}

// ---------------- P0 (fused prep): emb->ebf+enorm, z->zb16, zero accumulators -------
// 3072 blocks x 256 thr. Blocks [0,2048): emb fp32 -> ebf bf16 + enorm (4 rows/blk,
// wave/row); blocks [0,64) additionally zero candCnt; block 0 zeros lossAcc+doneCnt.
// Blocks [2048,3072): z BCHW fp32 -> zb16[n][c] bf16 (grid dim3(16,4,16) linearized
// as b2 = bid-2048: x=b2&15, y=(b2>>4)&3, b=b2>>6).
__global__ void k_prep(const float* __restrict__ z, const float* __restrict__ emb,
                       unsigned short* __restrict__ zb16, unsigned short* __restrict__ ebf,
                       float* __restrict__ enorm, float* __restrict__ lossAcc,
                       int* __restrict__ doneCnt, int* __restrict__ candCnt) {
    const int bid = blockIdx.x;
    const int tid = threadIdx.x;
    if (bid < 2048) {
        const int w = tid >> 6, lane = tid & 63;
        const int k = bid * 4 + w;
        const int i = k * CC + lane * 4;
        float4 v = *(const float4*)(emb + i);
        *(ushort4*)(ebf + i) = make_ushort4(f2bf(v.x), f2bf(v.y), f2bf(v.z), f2bf(v.w));
        float s = v.x * v.x + v.y * v.y + v.z * v.z + v.w * v.w;
        for (int off = 32; off > 0; off >>= 1) s += __shfl_down(s, off);
        if (lane == 0) enorm[k] = s;
        if (bid < 64) candCnt[bid * 256 + tid] = 0;
        if (bid == 0 && tid == 0) { lossAcc[0] = 0.0f; doneCnt[0] = 0; }
    } else {
        __shared__ float ts[64][65];
        const int b2 = bid - 2048;
        const int hw0 = (b2 & 15) * 64, c0 = ((b2 >> 4) & 3) * 64, b = b2 >> 6;
#pragma unroll
        for (int p = 0; p < 4; ++p) {
            int u = p * 256 + tid;
            int ci = u >> 4, j4 = (u & 15) << 2;
            float4 v = *(const float4*)(z + (size_t)b * 262144 + (size_t)(c0 + ci) * 1024 + hw0 + j4);
            ts[ci][j4 + 0] = v.x; ts[ci][j4 + 1] = v.y; ts[ci][j4 + 2] = v.z; ts[ci][j4 + 3] = v.w;
        }
        __syncthreads();
#pragma unroll
        for (int p = 0; p < 4; ++p) {
            int u = p * 256 + tid;
            int hj = u >> 4, i4 = (u & 15) << 2;
            ushort4 o = make_ushort4(f2bf(ts[i4 + 0][hj]), f2bf(ts[i4 + 1][hj]),
                                     f2bf(ts[i4 + 2][hj]), f2bf(ts[i4 + 3][hj]));
            *(ushort4*)(zb16 + (size_t)(b * 1024 + hw0 + hj) * 256 + c0 + i4) = o;
        }
    }
}

// ---------------- Phase 1: MFMA candidate gen, 3-waves/SIMD occupancy fix -----------
// OCCUPANCY MODEL (m97/m132 ladder: 2 waves/SIMD ~ 20% MfmaUtil, 3 waves/SIMD ~ 37%):
// all prior k_cand variants were 1 block/CU (LDS 82-124 KB) = 2 waves/SIMD, and every
// other lever (depth, schedule, traffic) landed at ~145us / 19% MfmaUtil. This round:
// 256-thr blocks (4 waves), LDS 48.5 KB, __launch_bounds__(256,3) (reg cap 170 >=
// need ~152 unified -- r6/r8 measured 88 VGPR + 64 AGPR) -> 3 blocks/CU = 3 waves/
// SIMD. Grid = dim3(3, 256): kq = k-third, nt = 64-n tile; 768 blocks all resident.
// k-thirds: 128 chunks (64 k each) split mod 3 (43/43/42). Wave w (0..3) handles
// chunk ordinal u = 4s+w, ci = 3u+kq, uniform 11-iter loop with `act` guard so the
// staleness barriers stay uniform. Inner loop = r6's verified A+B ping-pong.
// Candidates (r10-verified cross-block pattern): progressive threshold
// max(shared third-local runmax, own chunk max) - MARGIN -> LDS lists; block-end
// exact filter vs the block's TRUE third max; survivors -> GLOBAL candCnt/candI
// atomics. Soundness: dot(k*) >= M_global - MARGIN >= M_third - MARGIN, so the union
// over the 3 thirds contains the argmin. Any overflow -> candCnt+=KK -> full-scan
// fallback; total survivors > CAND_CAP also falls back (cnt > 64 check in k_final).
// mfma_f32_16x16x32_bf16: A[m=lane&15][c=(lane>>4)*8+j]; B[c][n=lane&15];
// D: col(n)=lane&15, row(k)=(lane>>4)*4+reg.
__global__ __launch_bounds__(256, 3)
void k_cand(const unsigned short* __restrict__ zb16, const unsigned short* __restrict__ ebf,
            int* __restrict__ candCnt, int* __restrict__ candI) {
    __shared__ short    Bs[8][4][512];      // 32 KB  [cchunk][ntile][lane*8]
    __shared__ unsigned runmaxU[64];        // ordered-uint running max per n (third-local)
    __shared__ int      cnt[64];
    __shared__ int      lstK[64][LCAP];     // 8 KB
    __shared__ float    lstD[64][LCAP];     // 8 KB

    const int tid  = threadIdx.x;
    const int lane = tid & 63;
    const int w    = tid >> 6;              // 0..3
    const int kq   = blockIdx.x;            // k-third 0..2
    const int nb   = blockIdx.y << 6;       // 64-n tile base
    const int m16  = lane & 15, q = lane >> 4;
    const int ulim = (127 - kq) / 3;        // 42,42,41: last active chunk ordinal

    if (tid < 64) { runmaxU[tid] = 0x007FFFFFu; /* fenc(-inf) */ cnt[tid] = 0; }

    // stage B-tile once: 32 (cc,nt) fragments x 64 lanes x 16B; 8 per wave
#pragma unroll
    for (int p = 0; p < 8; ++p) {
        const int g8 = p * 4 + w;          // 0..31, wave-uniform
        const int cc = g8 >> 2, nt = g8 & 3;
        const unsigned short* g = zb16 + (size_t)(nb + nt * 16 + m16) * 256 + cc * 32 + q * 8;
        gl_lds16(g, &Bs[cc][nt][lane * 8]);
    }

    auto loadA = [&](v8s (&a)[4], int kbr, int cc) {
#pragma unroll
        for (int kt = 0; kt < 4; ++kt)
            a[kt] = *(const v8s*)(ebf + (size_t)(kbr + (kt << 4) + m16) * 256 + (cc << 5) + q * 8);
    };
    auto loadB = [&](v8s (&b)[4], int cc) {
#pragma unroll
        for (int nt = 0; nt < 4; ++nt) b[nt] = *(const v8s*)&Bs[cc][nt][lane * 8];
    };

    v8s aP[4], aN[4], bP[4], bN[4];
    loadA(aP, (3 * w + kq) << 6, 0);       // first chunk (s=0 -> u=w), regs only
    __syncthreads();                       // Bs staged + runmaxU/cnt init visible
    loadB(bP, 0);

#pragma unroll 1
    for (int s = 0; s < 11; ++s) {
        const int u   = 4 * s + w;                      // chunk ordinal for this wave
        const bool act = (u <= ulim);
        const int kb  = (3 * u + kq) << 6;              // chunk base (64 k)
        const int kbn = (u + 4 <= ulim) ? kb + 768 : kb; // next chunk (u+4 -> ci+12)
        if (act) {
            v4f acc[16];
#pragma unroll
            for (int i = 0; i < 16; ++i) acc[i] = (v4f){0.f, 0.f, 0.f, 0.f};

#pragma unroll
            for (int cc = 0; cc < 8; ++cc) {
                if ((cc & 1) == 0) {
                    // consuming aP/bP; prefetch cc+1 into aN/bN
                    loadA(aN, kb, cc + 1);
                    loadB(bN, cc + 1);
#pragma unroll
                    for (int kt = 0; kt < 4; ++kt)
#pragma unroll
                        for (int nt = 0; nt < 4; ++nt)
                            acc[kt * 4 + nt] = __builtin_amdgcn_mfma_f32_16x16x32_bf16(
                                aP[kt], bP[nt], acc[kt * 4 + nt], 0, 0, 0);
                } else {
                    // consuming aN/bN; prefetch cc+1 (or next chunk cc0) into aP/bP
                    if (cc < 7) { loadA(aP, kb, cc + 1);  loadB(bP, cc + 1); }
                    else        { loadA(aP, kbn, 0);      loadB(bP, 0);      }
#pragma unroll
                    for (int kt = 0; kt < 4; ++kt)
#pragma unroll
                        for (int nt = 0; nt < 4; ++nt)
                            acc[kt * 4 + nt] = __builtin_amdgcn_mfma_f32_16x16x32_bf16(
                                aN[kt], bN[nt], acc[kt * 4 + nt], 0, 0, 0);
                }
            }

            // chunk epilogue: own-chunk max per n-column, merge into shared runmax, push
            float mx[4];
#pragma unroll
            for (int nt = 0; nt < 4; ++nt) {
                float m = acc[0 * 4 + nt][0];
#pragma unroll
                for (int kt = 0; kt < 4; ++kt)
#pragma unroll
                    for (int r = 0; r < 4; ++r) m = fmaxf(m, acc[kt * 4 + nt][r]);
                m = fmaxf(m, __shfl_xor(m, 16));
                m = fmaxf(m, __shfl_xor(m, 32));
                mx[nt] = m;                 // all lanes: chunk max of column nt*16+m16
                if (lane < 16) atomicMax(&runmaxU[nt * 16 + lane], fenc(m));
            }
#pragma unroll
            for (int nt = 0; nt < 4; ++nt) {
                const int nl = nt * 16 + m16;
                const float thr = fmaxf(fdec(runmaxU[nl]), mx[nt]) - MARGIN;
#pragma unroll
                for (int kt = 0; kt < 4; ++kt)
#pragma unroll
                    for (int r = 0; r < 4; ++r) {
                        if (acc[kt * 4 + nt][r] >= thr) {
                            int k = kb + (kt << 4) + q * 4 + r;
                            int pos = atomicAdd(&cnt[nl], 1);
                            if (pos < LCAP) { lstK[nl][pos] = k; lstD[nl][pos] = acc[kt * 4 + nt][r]; }
                        }
                    }
            }
        }
        if (s == 3 || s == 7) __syncthreads();   // bound cross-wave staleness (uniform)
    }

    __syncthreads();   // runmaxU now TRUE max of this block's k-third per n
    if (tid < 64) {
        const int n = nb + tid;
        const int c = cnt[tid];
        if (c > LCAP) {
            atomicAdd(&candCnt[n], KK);    // overflow -> force full-scan fallback
        } else {
            const float thr = fdec(runmaxU[tid]) - MARGIN;
            for (int i = 0; i < c; ++i) {
                if (lstD[tid][i] >= thr) {
                    int pos = atomicAdd(&candCnt[n], 1);
                    if (pos < CAND_CAP) candI[(size_t)n * CAND_CAP + pos] = lstK[tid][i];
                }
            }
        }
    }
}

// ---------------- Phase 2 (fused): stage + rescore + gather + loss (+finalize) ------
// 512 blocks x 256 thr (4 waves). Block = 32 consecutive hw (b = bid>>5, hw0 =
// (bid&31)*32); LDS 33.4 KB -> 4 blocks/CU. Rescore: wave per n (8 per wave), lane l
// holds zl[j][4l..4l+3]; zn butterfly shifts all d of an n equally -> argmin/
// tie-break invariant. d = (zn + enorm[k]) - (p+p); ties -> min k (order-invariant,
// robust to the nondeterministic cross-block candidate order). Loss finalized by the
// LAST block via doneCnt (device-scope atomics; __threadfence orders each block's
// lossAcc add before its doneCnt increment; no spin-wait anywhere -> no deadlock).
__global__ __launch_bounds__(256)
void k_final(const float* __restrict__ z, const float* __restrict__ emb,
             const float* __restrict__ enorm, const int* __restrict__ candCnt,
             const int* __restrict__ candI, float* __restrict__ out,
             float* __restrict__ idxf, float* __restrict__ lossAcc,
             int* __restrict__ doneCnt, float* __restrict__ outLoss) {
    __shared__ float zl[32][261];     // [hw][c], 33.4 KB
    __shared__ int   kis[32];
    __shared__ float red[256];
    const int bid = blockIdx.x;
    const int b = bid >> 5, hw0 = (bid & 31) << 5;
    const int tid = threadIdx.x;
    const int lane = tid & 63, w = tid >> 6;

    // stage: read float4 along hw (coalesced), transpose into zl[hw][c]
#pragma unroll
    for (int p = 0; p < 8; ++p) {
        const int u = p * 256 + tid;
        const int c = u >> 3, j4 = (u & 7) << 2;
        float4 v = *(const float4*)(z + (size_t)b * 262144 + (size_t)c * 1024 + hw0 + j4);
        zl[j4 + 0][c] = v.x; zl[j4 + 1][c] = v.y; zl[j4 + 2][c] = v.z; zl[j4 + 3][c] = v.w;
    }
    __syncthreads();

    // rescore: wave per n, 8 n per wave
#pragma unroll 1
    for (int rr = 0; rr < 8; ++rr) {
        const int j = w * 8 + rr;
        const int n = b * 1024 + hw0 + j;
        const float4 zv = *(const float4*)&zl[j][lane * 4];
        float zn = zv.x * zv.x;
        zn = fmaf(zv.y, zv.y, zn); zn = fmaf(zv.z, zv.z, zn); zn = fmaf(zv.w, zv.w, zn);
#pragma unroll
        for (int off = 1; off < 64; off <<= 1) zn += __shfl_xor(zn, off);
        const int cnt = candCnt[n];
        float bd = __builtin_inff();
        int   bk = 0x7fffffff;
        if (cnt <= CAND_CAP) {
#pragma unroll 1
            for (int i = 0; i < cnt; ++i) {
                const int k = candI[(size_t)n * CAND_CAP + i];
                const float4 ev = *(const float4*)(emb + (size_t)k * CC + lane * 4);
                float p = zv.x * ev.x;
                p = fmaf(zv.y, ev.y, p);
                p = fmaf(zv.z, ev.z, p);
                p = fmaf(zv.w, ev.w, p);
#pragma unroll
                for (int off = 1; off < 64; off <<= 1) p += __shfl_xor(p, off);
                const float d = (zn + enorm[k]) - (p + p);
                if (d < bd || (d == bd && k < bk)) { bd = d; bk = k; }
            }
        } else {
            // overflow fallback: exact full scan, ascending k keeps min-k
#pragma unroll 1
            for (int k = 0; k < KK; ++k) {
                const float4 ev = *(const float4*)(emb + (size_t)k * CC + lane * 4);
                float p = zv.x * ev.x;
                p = fmaf(zv.y, ev.y, p);
                p = fmaf(zv.z, ev.z, p);
                p = fmaf(zv.w, ev.w, p);
#pragma unroll
                for (int off = 1; off < 64; off <<= 1) p += __shfl_xor(p, off);
                const float d = (zn + enorm[k]) - (p + p);
                if (d < bd) { bd = d; bk = k; }
            }
        }
        if (lane == 0) { idxf[n] = (float)bk; kis[j] = bk; }
    }
    __syncthreads();

    // gather z_q (BCHW, coalesced along hw) + loss partials from the LDS tile
    const int j  = tid & 31;          // hw within tile
    const int cg = tid >> 5;          // c-group of 32
    const int ki0 = kis[j];
    const float* ep = emb + (size_t)ki0 * CC;
    float ls = 0.0f;
#pragma unroll 4
    for (int c = cg * 32; c < cg * 32 + 32; ++c) {
        float e  = ep[c];
        float zv = zl[j][c];
        out[(size_t)b * 262144 + (size_t)c * 1024 + hw0 + j] = e;
        float df = e - zv;
        ls = fmaf(df, df, ls);
    }
    red[tid] = ls;
    __syncthreads();
    for (int s2 = 128; s2 > 0; s2 >>= 1) {
        if (tid < s2) red[tid] += red[tid + s2];
        __syncthreads();
    }
    if (tid == 0) {
        atomicAdd(lossAcc, red[0]);
        __threadfence();                              // order lossAcc add before counter
        int old = atomicAdd(doneCnt, 1);
        if (old == (int)gridDim.x - 1) {              // last block finalizes loss
            float tot = atomicAdd(lossAcc, 0.0f);     // coherent read after all adds
            float m = tot * (1.0f / 4194304.0f);
            outLoss[0] = m + 0.25f * m;
        }
    }
}

extern "C" void kernel_launch(void* const* d_in, const int* in_sizes, int n_in,
                              void* d_out, int out_size, void* d_ws, size_t ws_size,
                              hipStream_t stream) {
    const float* z   = (const float*)d_in[0];
    const float* emb = (const float*)d_in[1];
    float* outf = (float*)d_out;
    float* wsf  = (float*)d_ws;

    float* lossAcc = wsf;
    int*   doneCnt = (int*)(wsf + 1);
    float* enorm   = wsf + WS_ENORM;
    int*   candCnt = (int*)(wsf + WS_CCNT);
    int*   candI   = (int*)(wsf + WS_CIDX);

    // d_out z_q region doubles as scratch: bf16 zb16/ebf until k_cand completes,
    // then k_final overwrites it with z_q.
    unsigned short* zb16 = (unsigned short*)outf;                  // 8 MB
    unsigned short* ebf  = (unsigned short*)(outf + 2097152);      // 4 MB

    k_prep<<<3072, 256, 0, stream>>>(z, emb, zb16, ebf, enorm, lossAcc, doneCnt, candCnt);
    k_cand<<<dim3(3, 256), 256, 0, stream>>>(zb16, ebf, candCnt, candI);
    k_final<<<512, 256, 0, stream>>>(z, emb, enorm, candCnt, candI,
                                     outf, outf + Z_OUT, lossAcc, doneCnt,
                                     outf + Z_OUT + NPTS);
}

// Round 12
// 319.519 us; speedup vs baseline: 11.6602x; 11.6602x over previous
//
#include <hip/hip_runtime.h>
#include <math.h>

// Problem constants
#define NB   16
#define CC   256
#define NPTS 16384       // 16*32*32
#define KK   8192
#define Z_OUT 4194304    // NPTS*CC
// d_out: [0,Z_OUT) z_q_out (BCHW), [Z_OUT,Z_OUT+NPTS) idx as float, [Z_OUT+NPTS] loss
// d_out scratch: zb16 = bf16[16384][256] at slot 0, ebf = bf16[8192][256] at slot
// 2,097,152 -- both dead once k_cand completes; k_final overwrites with z_q BCHW.

// ws layout (floats)
#define WS_ENORM 16448
#define WS_CCNT  24640                // int[16384] candidate counts
#define WS_CIDX  41024                // int[16384][64] candidate k lists
#define CAND_CAP 64
#define LCAP     64                   // per-third per-n LDS list capacity (packed 4B)
#define MARGIN   4.0e-4f              // > 2*eps_bf16 + d-quantum + enorm spread
#define BF_GUARD 4.0e-5f              // covers bf16 packing of stored dots

typedef short v8s __attribute__((ext_vector_type(8)));
typedef float v4f __attribute__((ext_vector_type(4)));

__device__ __forceinline__ void gl_lds16(const void* g, void* l) {
    __builtin_amdgcn_global_load_lds((const __attribute__((address_space(1))) void*)g,
                                     (__attribute__((address_space(3))) void*)l, 16, 0, 0);
}
__device__ __forceinline__ unsigned short f2bf(float f) {   // RNE, finite inputs
    unsigned int u = __float_as_uint(f);
    return (unsigned short)((u + 0x7FFFu + ((u >> 16) & 1u)) >> 16);
}
__device__ __forceinline__ float bf2f(unsigned short s) {
    return __uint_as_float(((unsigned)s) << 16);
}
// monotone float<->uint encoding for atomicMax on floats of any sign
__device__ __forceinline__ unsigned fenc(float f) {
    unsigned u = __float_as_uint(f);
    return (u & 0x80000000u) ? ~u : (u | 0x80000000u);
}
__device__ __forceinline__ float fdec(unsigned m) {
    unsigned u = (m & 0x80000000u) ? (m & 0x7fffffffu) : ~m;
    return __uint_as_float(u);
}

// ---------------- P0 (fused prep): emb->ebf+enorm, z->zb16, zero accumulators -------
// 3072 blocks x 256 thr. Blocks [0,2048): emb fp32 -> ebf bf16 + enorm (4 rows/blk,
// wave/row); blocks [0,64) additionally zero candCnt; block 0 zeros lossAcc+doneCnt.
// Blocks [2048,3072): z BCHW fp32 -> zb16[n][c] bf16 (grid dim3(16,4,16) linearized
// as b2 = bid-2048: x=b2&15, y=(b2>>4)&3, b=b2>>6).
__global__ void k_prep(const float* __restrict__ z, const float* __restrict__ emb,
                       unsigned short* __restrict__ zb16, unsigned short* __restrict__ ebf,
                       float* __restrict__ enorm, float* __restrict__ lossAcc,
                       int* __restrict__ doneCnt, int* __restrict__ candCnt) {
    const int bid = blockIdx.x;
    const int tid = threadIdx.x;
    if (bid < 2048) {
        const int w = tid >> 6, lane = tid & 63;
        const int k = bid * 4 + w;
        const int i = k * CC + lane * 4;
        float4 v = *(const float4*)(emb + i);
        *(ushort4*)(ebf + i) = make_ushort4(f2bf(v.x), f2bf(v.y), f2bf(v.z), f2bf(v.w));
        float s = v.x * v.x + v.y * v.y + v.z * v.z + v.w * v.w;
        for (int off = 32; off > 0; off >>= 1) s += __shfl_down(s, off);
        if (lane == 0) enorm[k] = s;
        if (bid < 64) candCnt[bid * 256 + tid] = 0;
        if (bid == 0 && tid == 0) { lossAcc[0] = 0.0f; doneCnt[0] = 0; }
    } else {
        __shared__ float ts[64][65];
        const int b2 = bid - 2048;
        const int hw0 = (b2 & 15) * 64, c0 = ((b2 >> 4) & 3) * 64, b = b2 >> 6;
#pragma unroll
        for (int p = 0; p < 4; ++p) {
            int u = p * 256 + tid;
            int ci = u >> 4, j4 = (u & 15) << 2;
            float4 v = *(const float4*)(z + (size_t)b * 262144 + (size_t)(c0 + ci) * 1024 + hw0 + j4);
            ts[ci][j4 + 0] = v.x; ts[ci][j4 + 1] = v.y; ts[ci][j4 + 2] = v.z; ts[ci][j4 + 3] = v.w;
        }
        __syncthreads();
#pragma unroll
        for (int p = 0; p < 4; ++p) {
            int u = p * 256 + tid;
            int hj = u >> 4, i4 = (u & 15) << 2;
            ushort4 o = make_ushort4(f2bf(ts[i4 + 0][hj]), f2bf(ts[i4 + 1][hj]),
                                     f2bf(ts[i4 + 2][hj]), f2bf(ts[i4 + 3][hj]));
            *(ushort4*)(zb16 + (size_t)(b * 1024 + hw0 + hj) * 256 + c0 + i4) = o;
        }
    }
}

// ---------------- Phase 1: MFMA candidate gen, 3-waves/SIMD occupancy test ----------
// Round-11 structure with the overflow fixed (r11 lesson: LCAP=32 < early-burst
// pushes ~20-35 -> every n overflowed -> k_final full-scan fallback 3.5ms). Lists
// are PACKED to 4B/entry (k ushort, dot bf16) so LCAP=64 fits the 3-blocks/CU LDS
// budget: Bs 32K + lists 16K + 0.5K = 49.7 KB <= 53.3 KB. Final filter widened by
// BF_GUARD (bf16 storage rounding <= 1.4e-5 abs) -- superset-only, exactness kept.
// 256-thr blocks (4 waves), __launch_bounds__(256,3): reg cap 170 >= need ~152
// (r6/r8: 88 VGPR + 64 AGPR) -> 3 blocks/CU = 3 waves/SIMD = 12 waves/CU.
// Grid dim3(3,256): kq = k-third, 64-n tile. k-thirds: 128 chunks (64 k) mod 3;
// wave w handles chunk ordinal u=4s+w, ci=3u+kq, uniform 11-iter loop + act guard.
// Inner loop = r6-verified A+B ping-pong. Candidates (r10-verified pattern):
// progressive thr = max(shared third-local runmax, own chunk max) - MARGIN (superset-
// safe under staleness) -> packed LDS lists; block-end exact filter vs TRUE third max
// (- BF_GUARD); survivors -> global candCnt/candI atomics. Soundness: dot(k*) >=
// M_global - MARGIN >= M_third - MARGIN. Overflow -> candCnt+=KK -> full-scan.
// mfma_f32_16x16x32_bf16: A[m=lane&15][c=(lane>>4)*8+j]; B[c][n=lane&15];
// D: col(n)=lane&15, row(k)=(lane>>4)*4+reg.
__global__ __launch_bounds__(256, 3)
void k_cand(const unsigned short* __restrict__ zb16, const unsigned short* __restrict__ ebf,
            int* __restrict__ candCnt, int* __restrict__ candI) {
    __shared__ short          Bs[8][4][512];    // 32 KB  [cchunk][ntile][lane*8]
    __shared__ unsigned       runmaxU[64];      // ordered-uint running max per n
    __shared__ int            cnt[64];
    __shared__ unsigned short lstK[64][LCAP];   // 8 KB (k < 8192 fits ushort)
    __shared__ unsigned short lstD[64][LCAP];   // 8 KB (dot packed bf16)

    const int tid  = threadIdx.x;
    const int lane = tid & 63;
    const int w    = tid >> 6;              // 0..3
    const int kq   = blockIdx.x;            // k-third 0..2
    const int nb   = blockIdx.y << 6;       // 64-n tile base
    const int m16  = lane & 15, q = lane >> 4;
    const int ulim = (127 - kq) / 3;        // 42,42,41: last active chunk ordinal

    if (tid < 64) { runmaxU[tid] = 0x007FFFFFu; /* fenc(-inf) */ cnt[tid] = 0; }

    // stage B-tile once: 32 (cc,nt) fragments x 64 lanes x 16B; 8 per wave
#pragma unroll
    for (int p = 0; p < 8; ++p) {
        const int g8 = p * 4 + w;          // 0..31, wave-uniform
        const int cc = g8 >> 2, nt = g8 & 3;
        const unsigned short* g = zb16 + (size_t)(nb + nt * 16 + m16) * 256 + cc * 32 + q * 8;
        gl_lds16(g, &Bs[cc][nt][lane * 8]);
    }

    auto loadA = [&](v8s (&a)[4], int kbr, int cc) {
#pragma unroll
        for (int kt = 0; kt < 4; ++kt)
            a[kt] = *(const v8s*)(ebf + (size_t)(kbr + (kt << 4) + m16) * 256 + (cc << 5) + q * 8);
    };
    auto loadB = [&](v8s (&b)[4], int cc) {
#pragma unroll
        for (int nt = 0; nt < 4; ++nt) b[nt] = *(const v8s*)&Bs[cc][nt][lane * 8];
    };

    v8s aP[4], aN[4], bP[4], bN[4];
    loadA(aP, (3 * w + kq) << 6, 0);       // first chunk (s=0 -> u=w), regs only
    __syncthreads();                       // Bs staged + runmaxU/cnt init visible
    loadB(bP, 0);

#pragma unroll 1
    for (int s = 0; s < 11; ++s) {
        const int u   = 4 * s + w;                      // chunk ordinal for this wave
        const bool act = (u <= ulim);
        const int kb  = (3 * u + kq) << 6;              // chunk base (64 k)
        const int kbn = (u + 4 <= ulim) ? kb + 768 : kb; // next chunk (u+4 -> ci+12)
        if (act) {
            v4f acc[16];
#pragma unroll
            for (int i = 0; i < 16; ++i) acc[i] = (v4f){0.f, 0.f, 0.f, 0.f};

#pragma unroll
            for (int cc = 0; cc < 8; ++cc) {
                if ((cc & 1) == 0) {
                    // consuming aP/bP; prefetch cc+1 into aN/bN
                    loadA(aN, kb, cc + 1);
                    loadB(bN, cc + 1);
#pragma unroll
                    for (int kt = 0; kt < 4; ++kt)
#pragma unroll
                        for (int nt = 0; nt < 4; ++nt)
                            acc[kt * 4 + nt] = __builtin_amdgcn_mfma_f32_16x16x32_bf16(
                                aP[kt], bP[nt], acc[kt * 4 + nt], 0, 0, 0);
                } else {
                    // consuming aN/bN; prefetch cc+1 (or next chunk cc0) into aP/bP
                    if (cc < 7) { loadA(aP, kb, cc + 1);  loadB(bP, cc + 1); }
                    else        { loadA(aP, kbn, 0);      loadB(bP, 0);      }
#pragma unroll
                    for (int kt = 0; kt < 4; ++kt)
#pragma unroll
                        for (int nt = 0; nt < 4; ++nt)
                            acc[kt * 4 + nt] = __builtin_amdgcn_mfma_f32_16x16x32_bf16(
                                aN[kt], bN[nt], acc[kt * 4 + nt], 0, 0, 0);
                }
            }

            // chunk epilogue: own-chunk max per n-column, merge into shared runmax, push
            float mx[4];
#pragma unroll
            for (int nt = 0; nt < 4; ++nt) {
                float m = acc[0 * 4 + nt][0];
#pragma unroll
                for (int kt = 0; kt < 4; ++kt)
#pragma unroll
                    for (int r = 0; r < 4; ++r) m = fmaxf(m, acc[kt * 4 + nt][r]);
                m = fmaxf(m, __shfl_xor(m, 16));
                m = fmaxf(m, __shfl_xor(m, 32));
                mx[nt] = m;                 // all lanes: chunk max of column nt*16+m16
                if (lane < 16) atomicMax(&runmaxU[nt * 16 + lane], fenc(m));
            }
#pragma unroll
            for (int nt = 0; nt < 4; ++nt) {
                const int nl = nt * 16 + m16;
                const float thr = fmaxf(fdec(runmaxU[nl]), mx[nt]) - MARGIN;
#pragma unroll
                for (int kt = 0; kt < 4; ++kt)
#pragma unroll
                    for (int r = 0; r < 4; ++r) {
                        if (acc[kt * 4 + nt][r] >= thr) {
                            int k = kb + (kt << 4) + q * 4 + r;
                            int pos = atomicAdd(&cnt[nl], 1);
                            if (pos < LCAP) {
                                lstK[nl][pos] = (unsigned short)k;
                                lstD[nl][pos] = f2bf(acc[kt * 4 + nt][r]);
                            }
                        }
                    }
            }
        }
        if (s == 3 || s == 7) __syncthreads();   // bound cross-wave staleness (uniform)
    }

    __syncthreads();   // runmaxU now TRUE max of this block's k-third per n
    if (tid < 64) {
        const int n = nb + tid;
        const int c = cnt[tid];
        if (c > LCAP) {
            atomicAdd(&candCnt[n], KK);    // overflow -> force full-scan fallback
        } else {
            // widened by BF_GUARD: stored dots are bf16-rounded (abs err <= ~1.4e-5)
            const float thr = fdec(runmaxU[tid]) - MARGIN - BF_GUARD;
            for (int i = 0; i < c; ++i) {
                if (bf2f(lstD[tid][i]) >= thr) {
                    int pos = atomicAdd(&candCnt[n], 1);
                    if (pos < CAND_CAP) candI[(size_t)n * CAND_CAP + pos] = (int)lstK[tid][i];
                }
            }
        }
    }
}

// ---------------- Phase 2 (fused): stage + rescore + gather + loss (+finalize) ------
// 512 blocks x 256 thr (4 waves). Block = 32 consecutive hw (b = bid>>5, hw0 =
// (bid&31)*32); LDS 33.4 KB -> 4 blocks/CU. Rescore: wave per n (8 per wave), lane l
// holds zl[j][4l..4l+3]; zn butterfly shifts all d of an n equally -> argmin/
// tie-break invariant. d = (zn + enorm[k]) - (p+p); ties -> min k (order-invariant,
// robust to the nondeterministic cross-block candidate order). Loss finalized by the
// LAST block via doneCnt (device-scope atomics; __threadfence orders each block's
// lossAcc add before its doneCnt increment; no spin-wait anywhere -> no deadlock).
__global__ __launch_bounds__(256)
void k_final(const float* __restrict__ z, const float* __restrict__ emb,
             const float* __restrict__ enorm, const int* __restrict__ candCnt,
             const int* __restrict__ candI, float* __restrict__ out,
             float* __restrict__ idxf, float* __restrict__ lossAcc,
             int* __restrict__ doneCnt, float* __restrict__ outLoss) {
    __shared__ float zl[32][261];     // [hw][c], 33.4 KB
    __shared__ int   kis[32];
    __shared__ float red[256];
    const int bid = blockIdx.x;
    const int b = bid >> 5, hw0 = (bid & 31) << 5;
    const int tid = threadIdx.x;
    const int lane = tid & 63, w = tid >> 6;

    // stage: read float4 along hw (coalesced), transpose into zl[hw][c]
#pragma unroll
    for (int p = 0; p < 8; ++p) {
        const int u = p * 256 + tid;
        const int c = u >> 3, j4 = (u & 7) << 2;
        float4 v = *(const float4*)(z + (size_t)b * 262144 + (size_t)c * 1024 + hw0 + j4);
        zl[j4 + 0][c] = v.x; zl[j4 + 1][c] = v.y; zl[j4 + 2][c] = v.z; zl[j4 + 3][c] = v.w;
    }
    __syncthreads();

    // rescore: wave per n, 8 n per wave
#pragma unroll 1
    for (int rr = 0; rr < 8; ++rr) {
        const int j = w * 8 + rr;
        const int n = b * 1024 + hw0 + j;
        const float4 zv = *(const float4*)&zl[j][lane * 4];
        float zn = zv.x * zv.x;
        zn = fmaf(zv.y, zv.y, zn); zn = fmaf(zv.z, zv.z, zn); zn = fmaf(zv.w, zv.w, zn);
#pragma unroll
        for (int off = 1; off < 64; off <<= 1) zn += __shfl_xor(zn, off);
        const int cnt = candCnt[n];
        float bd = __builtin_inff();
        int   bk = 0x7fffffff;
        if (cnt <= CAND_CAP) {
#pragma unroll 1
            for (int i = 0; i < cnt; ++i) {
                const int k = candI[(size_t)n * CAND_CAP + i];
                const float4 ev = *(const float4*)(emb + (size_t)k * CC + lane * 4);
                float p = zv.x * ev.x;
                p = fmaf(zv.y, ev.y, p);
                p = fmaf(zv.z, ev.z, p);
                p = fmaf(zv.w, ev.w, p);
#pragma unroll
                for (int off = 1; off < 64; off <<= 1) p += __shfl_xor(p, off);
                const float d = (zn + enorm[k]) - (p + p);
                if (d < bd || (d == bd && k < bk)) { bd = d; bk = k; }
            }
        } else {
            // overflow fallback: exact full scan, ascending k keeps min-k
#pragma unroll 1
            for (int k = 0; k < KK; ++k) {
                const float4 ev = *(const float4*)(emb + (size_t)k * CC + lane * 4);
                float p = zv.x * ev.x;
                p = fmaf(zv.y, ev.y, p);
                p = fmaf(zv.z, ev.z, p);
                p = fmaf(zv.w, ev.w, p);
#pragma unroll
                for (int off = 1; off < 64; off <<= 1) p += __shfl_xor(p, off);
                const float d = (zn + enorm[k]) - (p + p);
                if (d < bd) { bd = d; bk = k; }
            }
        }
        if (lane == 0) { idxf[n] = (float)bk; kis[j] = bk; }
    }
    __syncthreads();

    // gather z_q (BCHW, coalesced along hw) + loss partials from the LDS tile
    const int j  = tid & 31;          // hw within tile
    const int cg = tid >> 5;          // c-group of 32
    const int ki0 = kis[j];
    const float* ep = emb + (size_t)ki0 * CC;
    float ls = 0.0f;
#pragma unroll 4
    for (int c = cg * 32; c < cg * 32 + 32; ++c) {
        float e  = ep[c];
        float zv = zl[j][c];
        out[(size_t)b * 262144 + (size_t)c * 1024 + hw0 + j] = e;
        float df = e - zv;
        ls = fmaf(df, df, ls);
    }
    red[tid] = ls;
    __syncthreads();
    for (int s2 = 128; s2 > 0; s2 >>= 1) {
        if (tid < s2) red[tid] += red[tid + s2];
        __syncthreads();
    }
    if (tid == 0) {
        atomicAdd(lossAcc, red[0]);
        __threadfence();                              // order lossAcc add before counter
        int old = atomicAdd(doneCnt, 1);
        if (old == (int)gridDim.x - 1) {              // last block finalizes loss
            float tot = atomicAdd(lossAcc, 0.0f);     // coherent read after all adds
            float m = tot * (1.0f / 4194304.0f);
            outLoss[0] = m + 0.25f * m;
        }
    }
}

extern "C" void kernel_launch(void* const* d_in, const int* in_sizes, int n_in,
                              void* d_out, int out_size, void* d_ws, size_t ws_size,
                              hipStream_t stream) {
    const float* z   = (const float*)d_in[0];
    const float* emb = (const float*)d_in[1];
    float* outf = (float*)d_out;
    float* wsf  = (float*)d_ws;

    float* lossAcc = wsf;
    int*   doneCnt = (int*)(wsf + 1);
    float* enorm   = wsf + WS_ENORM;
    int*   candCnt = (int*)(wsf + WS_CCNT);
    int*   candI   = (int*)(wsf + WS_CIDX);

    // d_out z_q region doubles as scratch: bf16 zb16/ebf until k_cand completes,
    // then k_final overwrites it with z_q.
    unsigned short* zb16 = (unsigned short*)outf;                  // 8 MB
    unsigned short* ebf  = (unsigned short*)(outf + 2097152);      // 4 MB

    k_prep<<<3072, 256, 0, stream>>>(z, emb, zb16, ebf, enorm, lossAcc, doneCnt, candCnt);
    k_cand<<<dim3(3, 256), 256, 0, stream>>>(zb16, ebf, candCnt, candI);
    k_final<<<512, 256, 0, stream>>>(z, emb, enorm, candCnt, candI,
                                     outf, outf + Z_OUT, lossAcc, doneCnt,
                                     outf + Z_OUT + NPTS);
}